// Round 9
// baseline (870.092 us; speedup 1.0000x reference)
//
#include <hip/hip_runtime.h>

// LSTM_52922587021316 — Round 9: weights+biases in LDS, waves_per_eu PINNED.
// R3/R5/R7/R8 lesson: launch_bounds(256,w) leaves waves-per-EU max unpinned
// and the allocator squeezes VGPRs to a higher occupancy step, spilling
// (VGPR 64/48, FETCH 2+ GB). Fix: __attribute__((amdgpu_waves_per_eu(5,5)))
// pins both ends: cap 102 VGPR, no incentive to go lower.
// Diet to fit 5 waves/SIMD: all 3 weight matrices (prescaled f16 B-frags,
// 24 KB) + biases/rank-1 coeffs (packed {b0,wx} float2 + b1 float, 1.5 KB)
// in block-shared LDS; x staged as f16 (896 B); h areas 5 KB. Total 32128 B
// <= 32 KiB -> 5 blocks/CU. Natural VGPR need ~90 < 102 cap -> no spill.
// Keeps prescaled-gate activations + prescaled cell (cs = 2*log2e*c).
// Watch: VGPR_Count (90-102 = pin worked), FETCH_SIZE (~4 MB = clean).

#define HID 32
#define TSTEPS 7
#define LSTRIDE 40   // halves per LDS h-row: 32 + 8 pad (80 B, 16B-aligned)

typedef _Float16 half8 __attribute__((ext_vector_type(8)));
typedef _Float16 half4 __attribute__((ext_vector_type(4)));
typedef float floatx4 __attribute__((ext_vector_type(4)));
typedef float floatx2 __attribute__((ext_vector_type(2)));

#define LOG2E 1.44269504088896f

__device__ __forceinline__ float fast_rcp(float x) { return __builtin_amdgcn_rcpf(x); }

__device__ __forceinline__ float exp2_fast(float x) {
#if __has_builtin(__builtin_amdgcn_exp2f)
    return __builtin_amdgcn_exp2f(x);
#else
    return __expf(x * 0.69314718055994531f);
#endif
}

// s = -x*log2e pre-applied via weight prescale
__device__ __forceinline__ float sigm_pre(float s) {
    return fast_rcp(1.0f + exp2_fast(s));
}
// s = 2x*log2e pre-applied; returns tanh(x)
__device__ __forceinline__ float tanh_pre(float s) {
    return fmaf(-2.0f, fast_rcp(exp2_fast(s) + 1.0f), 1.0f);
}
// s = 2x*log2e pre-applied; returns (2*log2e)*tanh(x)  [prescaled-cell form]
__device__ __forceinline__ float tanh_pre_g(float s) {
    return fmaf(-4.0f * LOG2E, fast_rcp(exp2_fast(s) + 1.0f), 2.0f * LOG2E);
}

__global__ __launch_bounds__(256)
__attribute__((amdgpu_waves_per_eu(5, 5)))
void lstm2_mfma(
    const float* __restrict__ xin,   // [B, 7]
    const float* __restrict__ Wih0,  // [128, 1]
    const float* __restrict__ Whh0,  // [128, 32]
    const float* __restrict__ bih0,  // [128]
    const float* __restrict__ bhh0,  // [128]
    const float* __restrict__ Wih1,  // [128, 32]
    const float* __restrict__ Whh1,  // [128, 32]
    const float* __restrict__ bih1,  // [128]
    const float* __restrict__ bhh1,  // [128]
    const float* __restrict__ fcw,   // [32]
    const float* __restrict__ fcb,   // [1]
    const float* __restrict__ fc1w,  // [7]
    const float* __restrict__ fc1b,  // [1]
    float* __restrict__ out,         // [B]
    int B)
{
    const int tid  = threadIdx.x;
    const int lane = tid & 63;
    const int wave = tid >> 6;
    const int col  = lane & 15;          // C col / A row m
    const int rg   = lane >> 4;          // C rows rg*4..+3 / A k-chunk rg*8..+7
    const int seq_base = (blockIdx.x * 4 + wave) * 16;

    // [mat][nt][lane][8 halves]: mat 0 = Whh0, 1 = Wih1, 2 = Whh1
    __shared__ __align__(16) _Float16 ldsW[3][8][64][8];      // 24576 B
    __shared__ __align__(16) _Float16 ldsh[4][16 * LSTRIDE];  //  5120 B
    __shared__ __align__(16) _Float16 ldsx[4][TSTEPS * 16];   //   896 B
    __shared__ __align__(16) floatx2  ldsbA[128];             //  1024 B {b0s, wx}
    __shared__ __align__(16) float    ldsbB[128];             //   512 B {b1s}
    // total 32128 B <= 32768 -> 5 blocks/CU

    // ---- stage weight fragments to LDS (block-shared, once) --------------
    // frag element [m][nt][ln][j] = sc(n) * W[n = nt*16+(ln&15)][k=(ln>>4)*8+j]
    {
        const float* Wsrc[3] = {Whh0, Wih1, Whh1};
#pragma unroll
        for (int m = 0; m < 3; ++m) {
#pragma unroll
            for (int f = 0; f < 2; ++f) {
                const int idx = tid * 2 + f;          // 0..511
                const int nt = idx >> 6, ln = idx & 63;
                const int n  = nt * 16 + (ln & 15);
                const int k0 = (ln >> 4) * 8;
                const float sc = ((n >> 5) == 2) ? (2.0f * LOG2E) : (-LOG2E);
                const float* s = Wsrc[m] + n * HID + k0;
                half8 fr;
#pragma unroll
                for (int j = 0; j < 8; ++j) fr[j] = (_Float16)(sc * s[j]);
                *(half8*)&ldsW[m][nt][ln][0] = fr;
            }
        }
    }
    // ---- stage biases / rank-1 coeffs (first 128 threads) ----------------
    if (tid < 128) {
        const int n = tid;
        const float sc = ((n >> 5) == 2) ? (2.0f * LOG2E) : (-LOG2E);
        floatx2 bw;
        bw[0] = sc * (bih0[n] + bhh0[n]);
        bw[1] = sc * Wih0[n];
        ldsbA[n] = bw;
        ldsbB[n] = sc * (bih1[n] + bhh1[n]);
    }
    // ---- stage x as f16, transposed [t][m] per wave ----------------------
#pragma unroll
    for (int e = lane; e < TSTEPS * 16; e += 64) {
        const int s = e / TSTEPS;
        const int tt = e - s * TSTEPS;
        ldsx[wave][tt * 16 + s] = (_Float16)xin[seq_base * TSTEPS + e];
    }

    const float fcw_l0 = fcw[col];
    const float fcw_l1 = fcw[16 + col];

    __syncthreads();   // staging visible to all waves

    const _Float16* wbase = &ldsW[0][0][lane][0];   // frag (m,nt) at +((m*8+nt)*512) halves
    _Float16* hl = &ldsh[wave][0];

    half8 Ah1 = {};      // h1 in A-layout (zero at t=0)
    half8 Ah2 = {};      // h2 in A-layout
    float c1[2][4] = {}, c2[2][4] = {};  // prescaled: cs = 2*log2e*c
    float facc[4] = {0.f, 0.f, 0.f, 0.f};

#pragma unroll 1
    for (int t = 0; t < TSTEPS; ++t) {
        const half4 xh = *(const half4*)&ldsx[wave][t * 16 + rg * 4];
        float xr[4];
#pragma unroll
        for (int r = 0; r < 4; ++r) xr[r] = (float)xh[r];

        // -------- layer 0: gates = (bias + x*Wih0) + h1_prev @ Whh0^T -----
        floatx4 g0[8];
#pragma unroll
        for (int nt = 0; nt < 8; ++nt) {
            const floatx2 bw = ldsbA[nt * 16 + col];
            const half8 w = *(const half8*)(wbase + nt * 512);
            floatx4 c;
#pragma unroll
            for (int r = 0; r < 4; ++r) c[r] = fmaf(bw[1], xr[r], bw[0]);
            g0[nt] = __builtin_amdgcn_mfma_f32_16x16x32_f16(Ah1, w, c, 0, 0, 0);
        }

        // epilogue 0: cell update (prescaled cs), write h1_new to LDS
#pragma unroll
        for (int q = 0; q < 2; ++q) {
#pragma unroll
            for (int r = 0; r < 4; ++r) {
                const float ii = sigm_pre(g0[0 + q][r]);
                const float ff = sigm_pre(g0[2 + q][r]);
                const float gg = tanh_pre_g(g0[4 + q][r]);   // 2L*tanh(g)
                const float oo = sigm_pre(g0[6 + q][r]);
                const float cs = ff * c1[q][r] + ii * gg;    // = 2L*c
                c1[q][r] = cs;
                const float h = oo * tanh_pre(cs);           // tanh(c)
                hl[(rg * 4 + r) * LSTRIDE + q * 16 + col] = (_Float16)h;
            }
        }
        Ah1 = *(const half8*)&hl[col * LSTRIDE + rg * 8];

        // -------- layer 1: gates = bias + h1_new @ Wih1^T + h2_prev @ Whh1^T
        floatx4 g1[8];
#pragma unroll
        for (int nt = 0; nt < 8; ++nt) {
            const float b1 = ldsbB[nt * 16 + col];
            const half8 wa = *(const half8*)(wbase + (8 + nt) * 512);
            const half8 wb = *(const half8*)(wbase + (16 + nt) * 512);
            floatx4 c = {b1, b1, b1, b1};
            c = __builtin_amdgcn_mfma_f32_16x16x32_f16(Ah1, wa, c, 0, 0, 0);
            g1[nt] = __builtin_amdgcn_mfma_f32_16x16x32_f16(Ah2, wb, c, 0, 0, 0);
        }

        // epilogue 1: cell update, fc partial, write h2_new to LDS (same area)
        const float f1t = fc1w[t];
        const float w0 = f1t * fcw_l0;
        const float w1 = f1t * fcw_l1;
#pragma unroll
        for (int q = 0; q < 2; ++q) {
            const float wq = q ? w1 : w0;
#pragma unroll
            for (int r = 0; r < 4; ++r) {
                const float ii = sigm_pre(g1[0 + q][r]);
                const float ff = sigm_pre(g1[2 + q][r]);
                const float gg = tanh_pre_g(g1[4 + q][r]);
                const float oo = sigm_pre(g1[6 + q][r]);
                const float cs = ff * c2[q][r] + ii * gg;
                c2[q][r] = cs;
                const float h = oo * tanh_pre(cs);
                facc[r] = fmaf(wq, h, facc[r]);
                hl[(rg * 4 + r) * LSTRIDE + q * 16 + col] = (_Float16)h;
            }
        }
        Ah2 = *(const half8*)&hl[col * LSTRIDE + rg * 8];
    }

    // ---- reduce fc partials across the 16 cols, add constant tail --------
#pragma unroll
    for (int r = 0; r < 4; ++r) {
        float v = facc[r];
        v += __shfl_xor(v, 1);
        v += __shfl_xor(v, 2);
        v += __shfl_xor(v, 4);
        v += __shfl_xor(v, 8);
        facc[r] = v;
    }
    float sum_f1 = 0.f;
#pragma unroll
    for (int t = 0; t < TSTEPS; ++t) sum_f1 += fc1w[t];
    const float tail = fcb[0] * sum_f1 + fc1b[0];

    if (col == 0) {
#pragma unroll
        for (int r = 0; r < 4; ++r)
            out[seq_base + rg * 4 + r] = facc[r] + tail;
    }
}

extern "C" void kernel_launch(void* const* d_in, const int* in_sizes, int n_in,
                              void* d_out, int out_size, void* d_ws, size_t ws_size,
                              hipStream_t stream) {
    const float* xin  = (const float*)d_in[0];
    const float* Wih0 = (const float*)d_in[1];
    const float* Whh0 = (const float*)d_in[2];
    const float* bih0 = (const float*)d_in[3];
    const float* bhh0 = (const float*)d_in[4];
    const float* Wih1 = (const float*)d_in[5];
    const float* Whh1 = (const float*)d_in[6];
    const float* bih1 = (const float*)d_in[7];
    const float* bhh1 = (const float*)d_in[8];
    const float* fcw  = (const float*)d_in[9];
    const float* fcb  = (const float*)d_in[10];
    const float* fc1w = (const float*)d_in[11];
    const float* fc1b = (const float*)d_in[12];
    float* out = (float*)d_out;

    const int B = in_sizes[0] / TSTEPS;   // [B, T, F=1]
    const int grid = B / 64;              // 1 block = 4 waves = 64 sequences
    lstm2_mfma<<<grid, 256, 0, stream>>>(
        xin, Wih0, Whh0, bih0, bhh0, Wih1, Whh1, bih1, bhh1,
        fcw, fcb, fc1w, fc1b, out, B);
}